// Round 7
// baseline (1228.706 us; speedup 1.0000x reference)
//
#include <hip/hip_runtime.h>
#include <math.h>

#define B_ 32
#define N_ 4096

typedef __attribute__((ext_vector_type(8))) short short8;
typedef __attribute__((ext_vector_type(4))) float f32x4;
typedef __attribute__((ext_vector_type(2))) float v2f;
typedef __attribute__((ext_vector_type(2))) unsigned u32x2;
typedef __attribute__((ext_vector_type(2))) unsigned long long u64x2;

// fp32 -> bf16 round-to-nearest-even, and split x = hi + lo (both bf16).
__device__ __forceinline__ unsigned short f2bf(float f) {
    unsigned u = __float_as_uint(f);
    unsigned r = 0x7FFFu + ((u >> 16) & 1u);
    return (unsigned short)((u + r) >> 16);
}
__device__ __forceinline__ float bf2f(unsigned short h) {
    return __uint_as_float(((unsigned)h) << 16);
}
__device__ __forceinline__ void f2bfpair(float v, short& h, short& l) {
    unsigned short hh = f2bf(v);
    h = (short)hh;
    l = (short)f2bf(v - bf2f(hh));
}

// ---------------------------------------------------------------------------
// Packed argmax key = (float_bits(dist)+BIAS << 32) | ~idx.
// BIAS = 0x3F800000. dist < 3 always (coords in [0,1)), so the biased high
// word lies in [0x3F800000, 0x7FC00000]: every key is a NORMAL POSITIVE
// double -> f64 compare == u64 compare of the bit pattern, so v_max_f64
// (1 instr) replaces cmp_u64+2*cndmask while remaining bit-exact: max dist
// wins, min idx on tie (low word = ~idx) — identical to reference
// first-index argmax. Keys > 0, so max with 0.0 is identity.
// ---------------------------------------------------------------------------
#define KEY_BIAS 0x3F800000u

__device__ __forceinline__ double mk_key(unsigned hi, unsigned lo) {
    u32x2 p;
    p[0] = lo;
    p[1] = hi;
    return __builtin_bit_cast(double, p);
}
template<int CTRL>
__device__ __forceinline__ double dpp_dbl(double k) {
    unsigned long long u = (unsigned long long)__double_as_longlong(k);
    int lo = __builtin_amdgcn_mov_dpp((int)(unsigned)u, CTRL, 0xf, 0xf, true);
    int hi = __builtin_amdgcn_mov_dpp((int)(unsigned)(u >> 32), CTRL, 0xf, 0xf, true);
    unsigned long long r = ((unsigned long long)(unsigned)hi << 32) | (unsigned)lo;
    return __longlong_as_double((long long)r);
}
// Leader-only result in LANE 63, pure DPP.
__device__ __forceinline__ double wave_argmax_dbl_leader(double key) {
    key = fmax(key, dpp_dbl<0x128>(key));     // row_ror:8
    key = fmax(key, dpp_dbl<0x124>(key));     // row_ror:4
    key = fmax(key, dpp_dbl<0x122>(key));     // row_ror:2
    key = fmax(key, dpp_dbl<0x121>(key));     // row_ror:1
    key = fmax(key, dpp_dbl<0x142>(key));     // row_bcast15
    key = fmax(key, dpp_dbl<0x143>(key));     // row_bcast31 -> lane 63
    return key;
}

// ---------------------------------------------------------------------------
// Producer/consumer slot for incremental FPS-point publishing:
//   xy = {x_bits, y_bits}; zs = {z_bits, seq = g+1}.
// Producer: store xy RELAXED at iteration g; store zs RELEASE at iteration
// g+1 (so the release's implicit vmcnt(0) only waits on >=1-iteration-old
// stores — zero critical-path stall). Consumer: spin RELAXED on seq, one
// ACQUIRE re-load, then read xy RELAXED (release/acquire pairing makes xy
// visible). qpub is hipMemsetAsync-zeroed each launch (re-poison safety).
// ---------------------------------------------------------------------------
struct __align__(16) QPub { unsigned long long xy, zs; };

__device__ __forceinline__ unsigned long long pk2(float a, float b) {
    return ((unsigned long long)__float_as_uint(b) << 32) | __float_as_uint(a);
}
__device__ __forceinline__ unsigned long long pkzs(float z, unsigned seq) {
    return ((unsigned long long)seq << 32) | __float_as_uint(z);
}

// ---------------------------------------------------------------------------
// Weight prep (device body): split 8 fp32 [R][C] mats into bf16 hi/lo
// [R][Cp]. perm=1 (sa2w0): column remap feat-first. Items >= gblk0 zero
// gfeat for the fused-maxpool atomics.
// ---------------------------------------------------------------------------
struct WDesc { const float* src; short* dh; short* dl; int R, C, Cp, blk0, perm; };
struct WDescs { WDesc d[8]; float* gfeat; int gblk0, gtotal; };

__device__ __forceinline__ void wprep_body(const WDescs& W, int blk, int tid) {
    if (blk >= W.gblk0) {
        const int i = (blk - W.gblk0) * 256 + tid;
        if (i < W.gtotal) W.gfeat[i] = 0.f;
        return;
    }
    int di = 0;
#pragma unroll
    for (int k = 1; k < 8; k++) di = (blk >= W.d[k].blk0) ? k : di;
    const WDesc D = W.d[di];
    const int i = (blk - D.blk0) * 256 + tid;
    if (i >= D.R * D.Cp) return;
    const int r = i / D.Cp, c = i % D.Cp;
    int cs;
    if (D.perm) cs = (c < 128) ? c + 3 : (c < 131 ? c - 128 : -1);
    else        cs = (c < D.C) ? c : -1;
    float v = (cs >= 0) ? D.src[r * D.C + cs] : 0.f;
    short h, l;
    f2bfpair(v, h, l);
    D.dh[i] = h; D.dl[i] = l;
}

// ---------------------------------------------------------------------------
// Ball-query scan: wave-per-query (ballot/mbcnt), exact fp32 math (same
// expression tree as the reference, contract off).
// ---------------------------------------------------------------------------
template<int N, int NS>
__device__ __forceinline__ void ballquery_scan(
    const float* __restrict__ base, float qx, float qy, float qz,
    int* __restrict__ dst, float r2, int lane) {
#pragma clang fp contract(off)
    const float qn = (qx * qx + qy * qy) + qz * qz;
    int cnt = 0, first = 0;
    for (int p0 = 0; p0 < N; p0 += 64) {
        const int p = p0 + lane;
        const float x = base[p * 3 + 0];
        const float y = base[p * 3 + 1];
        const float z = base[p * 3 + 2];
        const float pn = (x * x + y * y) + z * z;
        const float dot = (qx * x + qy * y) + qz * z;
        const float sqd = (qn + pn) - 2.0f * dot;
        const unsigned long long mask = __ballot(sqd <= r2);
        if (mask) {
            if (cnt == 0) first = p0 + __ffsll((unsigned long long)mask) - 1;
            const int prefix = __builtin_amdgcn_mbcnt_hi(
                (unsigned)(mask >> 32),
                __builtin_amdgcn_mbcnt_lo((unsigned)mask, 0));
            const bool in = (mask >> lane) & 1ull;
            const int pos = cnt + prefix;
            if (in && pos < NS) dst[pos] = p;
            cnt += __popcll(mask);
            if (cnt >= NS) break;
        }
    }
    for (int i = cnt + lane; i < NS; i += 64) dst[i] = first;
}

template<int N, int NS>
__device__ __forceinline__ void ballquery_body(
    const float* __restrict__ xyz, const float* __restrict__ newXyz,
    int* __restrict__ outIdx, int S, float r2, int qid, int lane) {
    const int b = qid / S;
    const float* q = newXyz + (size_t)qid * 3;
    ballquery_scan<N, NS>(xyz + (size_t)b * N * 3, q[0], q[1], q[2],
                          outIdx + (size_t)qid * NS, r2, lane);
}

// ---------------------------------------------------------------------------
// K1: fps1 + wprep + ballquery1 fused via producer/consumer.
// Blocks [0, FPSB): fps1 (one per batch, exact fp32, index-critical),
// publishing each selected point incrementally through qpub. s_setprio(1)
// protects the serial chain from co-resident worker issue pressure.
// Blocks [FPSB, FPSB+WBLK): workers — wprep grid-strided, then bq1
// queries grid-strided per wave, spin-waiting (s_sleep) on availability.
// Grid = FPSB + WBLK = 768 = 3 blocks/CU co-resident (ps is [N][3] =
// 48 KiB so 3 fit; fps blocks have lowest IDs -> dispatched first -> no
// producer-starvation).
// ---------------------------------------------------------------------------
template<int N, int NPOINT, int NT, int FPSB, int WBLK>
__global__ __launch_bounds__(NT, 3) void fps_bq1_kernel(
    const float* __restrict__ xyz, float* __restrict__ outXyz,
    int* __restrict__ outIdx1, float r2q, QPub* __restrict__ qpub,
    WDescs W, int witems) {
#pragma clang fp contract(off)
    const int t = threadIdx.x;
    const int lane = t & 63, wv = t >> 6;
    if (blockIdx.x >= FPSB) {
        // ---- worker: wprep, then bq1 consumers ----
        const int wb = blockIdx.x - FPSB;
        for (int item = wb; item < witems; item += WBLK)
            wprep_body(W, item, t);
        const int wgid = (wb << 2) | wv;
        for (int q = wgid; q < B_ * NPOINT; q += WBLK * 4) {
            const int g = q & (NPOINT - 1);
            QPub* qp = qpub + q;
            while ((unsigned)(__hip_atomic_load(&qp->zs, __ATOMIC_RELAXED,
                                                __HIP_MEMORY_SCOPE_AGENT) >> 32)
                   != (unsigned)(g + 1))
                __builtin_amdgcn_s_sleep(2);
            const unsigned long long wzs = __hip_atomic_load(
                &qp->zs, __ATOMIC_ACQUIRE, __HIP_MEMORY_SCOPE_AGENT);
            const unsigned long long wxy = __hip_atomic_load(
                &qp->xy, __ATOMIC_RELAXED, __HIP_MEMORY_SCOPE_AGENT);
            const float qx = __uint_as_float((unsigned)wxy);
            const float qy = __uint_as_float((unsigned)(wxy >> 32));
            const float qz = __uint_as_float((unsigned)wzs);
            ballquery_scan<N, 32>(xyz + (size_t)(q / NPOINT) * N * 3,
                                  qx, qy, qz,
                                  outIdx1 + (size_t)q * 32, r2q, lane);
        }
        return;
    }
    // ---- fps1 producer ----
    __builtin_amdgcn_s_setprio(1);
    const int b = blockIdx.x;
    constexpr int PPT = N / NT;
    constexpr int PP2 = PPT / 2;
    constexpr int NW = (NT + 63) / 64;    // == 4
    __shared__ float ps[N][3];
    __shared__ __align__(16) double red[2][NW];
    const float* base = xyz + (size_t)b * N * 3;
    for (int j = t; j < N; j += NT) {
        ps[j][0] = base[j * 3 + 0];
        ps[j][1] = base[j * 3 + 1];
        ps[j][2] = base[j * 3 + 2];
    }
    __syncthreads();
    v2f px2[PP2], py2[PP2], pz2[PP2], mn2[PP2];
    unsigned nA[PP2], nB[PP2];
#pragma unroll
    for (int j = 0; j < PP2; j++) {
        const int p0 = t + (2 * j) * NT;
        const int p1 = t + (2 * j + 1) * NT;
        px2[j] = (v2f){ps[p0][0], ps[p1][0]};
        py2[j] = (v2f){ps[p0][1], ps[p1][1]};
        pz2[j] = (v2f){ps[p0][2], ps[p1][2]};
        mn2[j] = (v2f){1e10f, 1e10f};
        nA[j] = ~(unsigned)p0;
        nB[j] = ~(unsigned)p1;
    }
#pragma unroll
    for (int j = 0; j < PP2; j++)
        asm volatile("" : "+v"(px2[j]), "+v"(py2[j]), "+v"(pz2[j]));
    float lx = ps[0][0], ly = ps[0][1], lz = ps[0][2];
    QPub* qp = qpub + (size_t)b * NPOINT;
    float* outB = outXyz + (size_t)b * NPOINT * 3;
    float pz_prev = lz;
    if (t == 0) {
        outB[0] = lx; outB[1] = ly; outB[2] = lz;
        __hip_atomic_store(&qp[0].xy, pk2(lx, ly), __ATOMIC_RELAXED,
                           __HIP_MEMORY_SCOPE_AGENT);
    }
    for (int it = 1; it < NPOINT; it++) {
        const v2f lx2 = (v2f){lx, lx};
        const v2f ly2 = (v2f){ly, ly};
        const v2f lz2 = (v2f){lz, lz};
        double k0 = 0.0, k1 = 0.0, k2 = 0.0, k3 = 0.0;
#pragma unroll
        for (int j = 0; j < PP2; j++) {
            v2f dx = px2[j] - lx2;
            v2f dy = py2[j] - ly2;
            v2f dz = pz2[j] - lz2;
            v2f t0 = dx * dx, t1 = dy * dy, t2 = dz * dz;
            v2f d2 = (t0 + t1) + t2;
            v2f m = __builtin_elementwise_min(mn2[j], d2);
            mn2[j] = m;
            double da = mk_key(__float_as_uint(m[0]) + KEY_BIAS, nA[j]);
            double db = mk_key(__float_as_uint(m[1]) + KEY_BIAS, nB[j]);
            if (j & 1) { k2 = fmax(k2, da); k3 = fmax(k3, db); }
            else       { k0 = fmax(k0, da); k1 = fmax(k1, db); }
        }
        double key = fmax(fmax(k0, k1), fmax(k2, k3));
        key = wave_argmax_dbl_leader(key);
        const int par = it & 1;
        if ((t & 63) == 63) red[par][t >> 6] = key;
        __syncthreads();
        u64x2 r01 = *(const u64x2*)&red[par][0];
        u64x2 r23 = *(const u64x2*)&red[par][2];
        double b0 = __longlong_as_double((long long)r01[0]);
        double b1 = __longlong_as_double((long long)r01[1]);
        double b2 = __longlong_as_double((long long)r23[0]);
        double b3 = __longlong_as_double((long long)r23[1]);
        double best = fmax(fmax(b0, b1), fmax(b2, b3));
        const int fi = (int)(~(unsigned)(unsigned long long)__double_as_longlong(best));
        lx = ps[fi][0]; ly = ps[fi][1]; lz = ps[fi][2];
        if (t == 0) {
            // deferred release: zs[it-1]'s paired stores are >=1 iter old,
            // so the release's vmcnt(0) wait is ~free.
            __hip_atomic_store(&qp[it - 1].zs, pkzs(pz_prev, (unsigned)it),
                               __ATOMIC_RELEASE, __HIP_MEMORY_SCOPE_AGENT);
            __hip_atomic_store(&qp[it].xy, pk2(lx, ly), __ATOMIC_RELAXED,
                               __HIP_MEMORY_SCOPE_AGENT);
            pz_prev = lz;
            outB[it * 3 + 0] = lx;
            outB[it * 3 + 1] = ly;
            outB[it * 3 + 2] = lz;
        }
    }
    if (t == 0)
        __hip_atomic_store(&qp[NPOINT - 1].zs, pkzs(pz_prev, (unsigned)NPOINT),
                           __ATOMIC_RELEASE, __HIP_MEMORY_SCOPE_AGENT);
}

// ---------------------------------------------------------------------------
// MFMA helpers (verified gfx950 16x16x32 bf16 layouts).
// Split fp32 = hi+lo bf16: D += Ah*Bh + Ah*Bl + Al*Bh
// ---------------------------------------------------------------------------
template<int NT, int KS>
__device__ __forceinline__ void mfma_layer(
    const short* Aph, const short* Apl, const int sA,
    const short* __restrict__ Wph, const short* __restrict__ Wpl, const int sW,
    f32x4* acc, const int n0, const int mh, const int lr, const int lq) {
#pragma unroll
    for (int ks = 0; ks < KS; ks++) {
        const int ka = ks * 32 + lq * 8;
        short8 a_h[2], a_l[2];
#pragma unroll
        for (int mt = 0; mt < 2; mt++) {
            const int m = (mh * 2 + mt) * 16 + lr;
            a_h[mt] = *(const short8*)(Aph + m * sA + ka);
            a_l[mt] = *(const short8*)(Apl + m * sA + ka);
        }
#pragma unroll
        for (int nt = 0; nt < NT; nt++) {
            const int n = n0 + nt * 16 + lr;
            short8 b_h = *(const short8*)(Wph + (size_t)n * sW + ka);
            short8 b_l = *(const short8*)(Wpl + (size_t)n * sW + ka);
#pragma unroll
            for (int mt = 0; mt < 2; mt++) {
                f32x4 c = acc[mt * NT + nt];
                c = __builtin_amdgcn_mfma_f32_16x16x32_bf16(a_h[mt], b_h, c, 0, 0, 0);
                c = __builtin_amdgcn_mfma_f32_16x16x32_bf16(a_h[mt], b_l, c, 0, 0, 0);
                c = __builtin_amdgcn_mfma_f32_16x16x32_bf16(a_l[mt], b_h, c, 0, 0, 0);
                acc[mt * NT + nt] = c;
            }
        }
    }
}

template<int NT>
__device__ __forceinline__ void init_bias(f32x4* acc, const float* __restrict__ bias,
                                          const int n0, const int lr) {
#pragma unroll
    for (int nt = 0; nt < NT; nt++) {
        float bv = bias[n0 + nt * 16 + lr];
        f32x4 c = {bv, bv, bv, bv};
        acc[0 * NT + nt] = c;
        acc[1 * NT + nt] = c;
    }
}

template<int NT>
__device__ __forceinline__ void store_split(
    const f32x4* acc, short* Hp, short* Lp, const int stride,
    const int n0, const int mh, const int lr, const int lq) {
#pragma unroll
    for (int mt = 0; mt < 2; mt++)
#pragma unroll
        for (int nt = 0; nt < NT; nt++)
#pragma unroll
            for (int r = 0; r < 4; r++) {
                float v = fmaxf(acc[mt * NT + nt][r], 0.f);
                short h, l;
                f2bfpair(v, h, l);
                const int m = (mh * 2 + mt) * 16 + lq * 4 + r;
                const int n = n0 + nt * 16 + lr;
                Hp[m * stride + n] = h;
                Lp[m * stride + n] = l;
            }
}

// ---------------------------------------------------------------------------
// K2: {fps2 + sa1}. Blocks [0, FPB) = fps2 (nxyz1 -> nxyz2, serial tail,
// lowest IDs = dispatched first, overlapped with sa1); blocks >= FPB = sa1.
// LDS shared via one arena (sa1's 37888 B; fps2's 8 KiB ps overlays it) so
// sa1 keeps 4 blocks/CU.
// ---------------------------------------------------------------------------
#define T1 72
#define ARENA_BYTES 37888
template<int FPB, int NF, int NPF>
__global__ __launch_bounds__(256) void fps2_sa1_kernel(
    const float* __restrict__ x, const float* __restrict__ nxyz1,
    const int* __restrict__ idx,
    const float* __restrict__ w0, const float* __restrict__ b0,
    const short* __restrict__ w1h, const short* __restrict__ w1l,
    const float* __restrict__ b1,
    const short* __restrict__ w2h, const short* __restrict__ w2l,
    const float* __restrict__ b2,
    short* __restrict__ feat1h, short* __restrict__ feat1l,
    float* __restrict__ outXyzF) {
    const int t = threadIdx.x;
    const int lane = t & 63, wv = t >> 6;
    __shared__ __align__(16) char arena[ARENA_BYTES];
    if (blockIdx.x < FPB) {
        // ---- fps2: single-wave serial FPS over NF points ----
#pragma clang fp contract(off)
        __builtin_amdgcn_s_setprio(1);
        float (*ps)[4] = (float(*)[4])arena;
        const int b = blockIdx.x;
        const float* base = nxyz1 + (size_t)b * NF * 3;
        for (int j = t; j < NF; j += 256) {
            ps[j][0] = base[j * 3 + 0];
            ps[j][1] = base[j * 3 + 1];
            ps[j][2] = base[j * 3 + 2];
        }
        __syncthreads();
        if (t >= 64) return;
        constexpr int PPT = NF / 64;
        constexpr int PP2 = PPT / 2;
        v2f px2[PP2], py2[PP2], pz2[PP2], mn2[PP2];
        unsigned nA[PP2], nB[PP2];
#pragma unroll
        for (int j = 0; j < PP2; j++) {
            const int p0 = t + (2 * j) * 64;
            const int p1 = t + (2 * j + 1) * 64;
            f32x4 a = *(const f32x4*)&ps[p0][0];
            f32x4 c = *(const f32x4*)&ps[p1][0];
            px2[j] = (v2f){a[0], c[0]};
            py2[j] = (v2f){a[1], c[1]};
            pz2[j] = (v2f){a[2], c[2]};
            mn2[j] = (v2f){1e10f, 1e10f};
            nA[j] = ~(unsigned)p0;
            nB[j] = ~(unsigned)p1;
        }
        float lx = ps[0][0], ly = ps[0][1], lz = ps[0][2];
        if (t == 0) {
            outXyzF[(size_t)b * NPF * 3 + 0] = lx;
            outXyzF[(size_t)b * NPF * 3 + 1] = ly;
            outXyzF[(size_t)b * NPF * 3 + 2] = lz;
        }
        for (int it = 1; it < NPF; it++) {
            const v2f lx2 = (v2f){lx, lx};
            const v2f ly2 = (v2f){ly, ly};
            const v2f lz2 = (v2f){lz, lz};
            double k0 = 0.0, k1 = 0.0;
#pragma unroll
            for (int j = 0; j < PP2; j++) {
                v2f dx = px2[j] - lx2;
                v2f dy = py2[j] - ly2;
                v2f dz = pz2[j] - lz2;
                v2f t0 = dx * dx, t1 = dy * dy, t2 = dz * dz;
                v2f d2 = (t0 + t1) + t2;
                v2f m = __builtin_elementwise_min(mn2[j], d2);
                mn2[j] = m;
                double da = mk_key(__float_as_uint(m[0]) + KEY_BIAS, nA[j]);
                double db = mk_key(__float_as_uint(m[1]) + KEY_BIAS, nB[j]);
                k0 = fmax(k0, da);
                k1 = fmax(k1, db);
            }
            double key = fmax(k0, k1);
            key = wave_argmax_dbl_leader(key);
            const int lo = __shfl(
                (int)(unsigned)(unsigned long long)__double_as_longlong(key), 63);
            const int fi = (int)(~(unsigned)lo);
            f32x4 c4 = *(const f32x4*)&ps[fi][0];
            lx = c4[0]; ly = c4[1]; lz = c4[2];
            if (t == 0) {
                outXyzF[((size_t)b * NPF + it) * 3 + 0] = lx;
                outXyzF[((size_t)b * NPF + it) * 3 + 1] = ly;
                outXyzF[((size_t)b * NPF + it) * 3 + 2] = lz;
            }
        }
        return;
    }
    // ---- sa1 ----
    const int g0 = (blockIdx.x - FPB) * 2;
    const int b = g0 >> 9;
    const int lr = lane & 15, lq = lane >> 4;
    const int mh = wv & 1, nh = wv >> 1;
    float (*gx)[4] = (float(*)[4])arena;                 // 1024 B
    short* H1h = (short*)(arena + 1024);                 // 9216 B
    short* H1l = (short*)(arena + 10240);                // 9216 B
    short* H2h = (short*)(arena + 19456);                // 9216 B
    short* H2l = (short*)(arena + 28672);                // 9216 B
    if (t < 64) {
        int g = g0 + (t >> 5);
        int id = idx[(size_t)g * 32 + (t & 31)];
        const float* pp = x + ((size_t)b * N_ + id) * 3;
        const float* cc = nxyz1 + (size_t)g * 3;
        gx[t][0] = pp[0] - cc[0];
        gx[t][1] = pp[1] - cc[1];
        gx[t][2] = pp[2] - cc[2];
    }
    __syncthreads();
    {   // layer1 K=3 via VALU
        const int m = t >> 2, oc = (t & 3) * 16;
        float a0 = gx[m][0], a1 = gx[m][1], a2 = gx[m][2];
        short8 hv0, hv1, lv0, lv1;
#pragma unroll
        for (int i = 0; i < 16; i++) {
            int o = oc + i;
            float v = fmaf(w0[o * 3 + 0], a0,
                      fmaf(w0[o * 3 + 1], a1,
                      fmaf(w0[o * 3 + 2], a2, b0[o])));
            v = fmaxf(v, 0.f);
            short h, l;
            f2bfpair(v, h, l);
            if (i < 8) { hv0[i] = h; lv0[i] = l; }
            else       { hv1[i - 8] = h; lv1[i - 8] = l; }
        }
        *(short8*)&H1h[m * T1 + oc]     = hv0;
        *(short8*)&H1h[m * T1 + oc + 8] = hv1;
        *(short8*)&H1l[m * T1 + oc]     = lv0;
        *(short8*)&H1l[m * T1 + oc + 8] = lv1;
    }
    __syncthreads();
    {   // layer2: K=64, N=64
        f32x4 acc[4];
        init_bias<2>(acc, b1, nh * 32, lr);
        mfma_layer<2, 2>(H1h, H1l, T1, w1h, w1l, 64, acc, nh * 32, mh, lr, lq);
        store_split<2>(acc, H2h, H2l, T1, nh * 32, mh, lr, lq);
    }
    __syncthreads();
    {   // layer3: K=64, N=128 + per-group max, split output
        f32x4 acc[8];
        init_bias<4>(acc, b2, nh * 64, lr);
        mfma_layer<4, 2>(H2h, H2l, T1, w2h, w2l, 64, acc, nh * 64, mh, lr, lq);
#pragma unroll
        for (int nt = 0; nt < 4; nt++) {
            float v = 0.f;
#pragma unroll
            for (int mt = 0; mt < 2; mt++)
#pragma unroll
                for (int r = 0; r < 4; r++)
                    v = fmaxf(v, acc[mt * 4 + nt][r]);
            v = fmaxf(v, __shfl_xor(v, 16));
            v = fmaxf(v, __shfl_xor(v, 32));
            if (lane < 16) {
                short h, l;
                f2bfpair(v, h, l);
                size_t o = (size_t)(g0 + mh) * 128 + nh * 64 + nt * 16 + lane;
                feat1h[o] = h;
                feat1l[o] = l;
            }
        }
    }
}

// K3: ballquery2 standalone (needs nxyz2 from K2's fps2).
__global__ __launch_bounds__(256) void bq2_kernel(
    const float* __restrict__ nxyz1, const float* __restrict__ nxyz2,
    int* __restrict__ idx2, float r2q) {
    const int t = threadIdx.x, lane = t & 63, wv = t >> 6;
    ballquery_body<512, 64>(nxyz1, nxyz2, idx2, 128, r2q,
                            blockIdx.x * 4 + wv, lane);
}

// ---------------------------------------------------------------------------
// SA2 MFMA: consumes feat1 planes (feat-first layout), outputs a3 planes.
// ---------------------------------------------------------------------------
#define S1 168
#define S2 136
__global__ __launch_bounds__(256) void sa2_mfma_kernel(
    const float* __restrict__ xyz1,
    const short* __restrict__ feat1h, const short* __restrict__ feat1l,
    const float* __restrict__ newXyz, const int* __restrict__ idx,
    const short* __restrict__ w0h, const short* __restrict__ w0l,
    const float* __restrict__ b0,
    const short* __restrict__ w1h, const short* __restrict__ w1l,
    const float* __restrict__ b1,
    const short* __restrict__ w2h, const short* __restrict__ w2l,
    const float* __restrict__ b2,
    short* __restrict__ a3h, short* __restrict__ a3l) {
    const int g = blockIdx.x;
    const int b = g >> 7;
    const int t = threadIdx.x;
    const int lane = t & 63, wv = t >> 6;
    const int lr = lane & 15, lq = lane >> 4;
    const int mh = wv & 1, nh = wv >> 1;
    __shared__ short Ah[64 * S1], Al[64 * S1];
    __shared__ short Hh[64 * S2], Hl[64 * S2];
    __shared__ float pmax[2][256];
    __shared__ int ids[64];
    if (t < 64) ids[t] = idx[(size_t)g * 64 + t];
    __syncthreads();
    {   // gather: feat cols 0..127 via b128 plane copies; xyz at 128..130
        const int m = t >> 2, q = t & 3;
        const int id = ids[m];
        const size_t frow = ((size_t)b * 512 + id) * 128;
#pragma unroll
        for (int c8 = 0; c8 < 4; c8++) {
            const int k = q * 32 + c8 * 8;
            *(short8*)&Ah[m * S1 + k] = *(const short8*)(feat1h + frow + k);
            *(short8*)&Al[m * S1 + k] = *(const short8*)(feat1l + frow + k);
        }
        if (t < 64) {
            const int id2 = ids[t];
            short8 zz = {0, 0, 0, 0, 0, 0, 0, 0};
            *(short8*)&Ah[t * S1 + 128] = zz;
            *(short8*)&Ah[t * S1 + 136] = zz;
            *(short8*)&Ah[t * S1 + 144] = zz;
            *(short8*)&Ah[t * S1 + 152] = zz;
            *(short8*)&Al[t * S1 + 128] = zz;
            *(short8*)&Al[t * S1 + 136] = zz;
            *(short8*)&Al[t * S1 + 144] = zz;
            *(short8*)&Al[t * S1 + 152] = zz;
            const float* prow = xyz1 + ((size_t)b * 512 + id2) * 3;
            const float* crow = newXyz + (size_t)g * 3;
#pragma unroll
            for (int c = 0; c < 3; c++) {
                short h, l;
                f2bfpair(prow[c] - crow[c], h, l);
                Ah[t * S1 + 128 + c] = h;
                Al[t * S1 + 128 + c] = l;
            }
        }
    }
    __syncthreads();
    {   // layer1: K=160, N=128
        f32x4 acc[8];
        init_bias<4>(acc, b0, nh * 64, lr);
        mfma_layer<4, 5>(Ah, Al, S1, w0h, w0l, 160, acc, nh * 64, mh, lr, lq);
        store_split<4>(acc, Hh, Hl, S2, nh * 64, mh, lr, lq);
    }
    __syncthreads();
    {   // layer2: K=128, N=128
        f32x4 acc[8];
        init_bias<4>(acc, b1, nh * 64, lr);
        mfma_layer<4, 4>(Hh, Hl, S2, w1h, w1l, 128, acc, nh * 64, mh, lr, lq);
        store_split<4>(acc, Ah, Al, S2, nh * 64, mh, lr, lq);
    }
    __syncthreads();
    {   // layer3: K=128, N=256 + max over 64 rows
        f32x4 acc[16];
        init_bias<8>(acc, b2, nh * 128, lr);
        mfma_layer<8, 4>(Ah, Al, S2, w2h, w2l, 128, acc, nh * 128, mh, lr, lq);
#pragma unroll
        for (int nt = 0; nt < 8; nt++) {
            float v = 0.f;
#pragma unroll
            for (int mt = 0; mt < 2; mt++)
#pragma unroll
                for (int r = 0; r < 4; r++)
                    v = fmaxf(v, acc[mt * 8 + nt][r]);
            v = fmaxf(v, __shfl_xor(v, 16));
            v = fmaxf(v, __shfl_xor(v, 32));
            if (lane < 16) pmax[mh][nh * 128 + nt * 16 + lane] = v;
        }
    }
    __syncthreads();
    {   // write a3 row g: col 3+t = feat, cols 0..2 xyz, 259..287 zero
        float v = fmaxf(pmax[0][t], pmax[1][t]);
        short h, l;
        f2bfpair(v, h, l);
        a3h[(size_t)g * 288 + 3 + t] = h;
        a3l[(size_t)g * 288 + 3 + t] = l;
        if (t < 3) {
            f2bfpair(newXyz[(size_t)g * 3 + t], h, l);
            a3h[(size_t)g * 288 + t] = h;
            a3l[(size_t)g * 288 + t] = l;
        }
        if (t >= 227) {
            a3h[(size_t)g * 288 + t + 32] = 0;
            a3l[(size_t)g * 288 + t + 32] = 0;
        }
    }
}

// ---------------------------------------------------------------------------
// MFMA GEMM: A pre-split planes [M][Kp]; weights pre-split planes [N][Kp].
// OUT_MODE 1: relu + split-plane output.
// OUT_MODE 2: relu + per-column block max + atomicMax into gfeat (fused
//   maxpool; values >=0 so int-compare on float bits is order-correct).
// ---------------------------------------------------------------------------
template<int OUT_MODE>
__global__ __launch_bounds__(256) void mfma_gemm_kernel(
    const short* __restrict__ Agh, const short* __restrict__ Agl, const int Kp,
    const short* __restrict__ Wh, const short* __restrict__ Wl,
    const float* __restrict__ bias,
    float* __restrict__ outF, short* __restrict__ outH,
    short* __restrict__ outL, const int N) {
    const int t = threadIdx.x;
    const int lane = t & 63, wv = t >> 6;
    const int lr = lane & 15, lq = lane >> 4;
    const int mh = wv & 1, nh = wv >> 1;
    const int m0 = blockIdx.y * 64;
    const int n0 = blockIdx.x * 128 + nh * 64;
    __shared__ short Ah[64 * 40], Al[64 * 40];
    f32x4 acc[8];
#pragma unroll
    for (int nt = 0; nt < 4; nt++) {
        float bv = bias[n0 + nt * 16 + lr];
        f32x4 c = {bv, bv, bv, bv};
        acc[nt] = c; acc[4 + nt] = c;
    }
    const int srow = t >> 2, sk = (t & 3) * 8;
    for (int kt = 0; kt < Kp; kt += 32) {
        {   // stage A chunk: pure b128 copies (no conversion)
            const size_t src = (size_t)(m0 + srow) * Kp + kt + sk;
            *(short8*)&Ah[srow * 40 + sk] = *(const short8*)(Agh + src);
            *(short8*)&Al[srow * 40 + sk] = *(const short8*)(Agl + src);
        }
        __syncthreads();
        short8 a_h[2], a_l[2];
#pragma unroll
        for (int mt = 0; mt < 2; mt++) {
            const int m = mh * 32 + mt * 16 + lr;
            a_h[mt] = *(const short8*)&Ah[m * 40 + lq * 8];
            a_l[mt] = *(const short8*)&Al[m * 40 + lq * 8];
        }
#pragma unroll
        for (int nt = 0; nt < 4; nt++) {
            const int n = n0 + nt * 16 + lr;
            short8 b_h = *(const short8*)(Wh + (size_t)n * Kp + kt + lq * 8);
            short8 b_l = *(const short8*)(Wl + (size_t)n * Kp + kt + lq * 8);
#pragma unroll
            for (int mt = 0; mt < 2; mt++) {
                f32x4 c = acc[mt * 4 + nt];
                c = __builtin_amdgcn_mfma_f32_16x16x32_bf16(a_h[mt], b_h, c, 0, 0, 0);
                c = __builtin_amdgcn_mfma_f32_16x16x32_bf16(a_h[mt], b_l, c, 0, 0, 0);
                c = __builtin_amdgcn_mfma_f32_16x16x32_bf16(a_l[mt], b_h, c, 0, 0, 0);
                acc[mt * 4 + nt] = c;
            }
        }
        __syncthreads();
    }
    if (OUT_MODE == 2) {
        const int batch = blockIdx.y >> 1;
#pragma unroll
        for (int nt = 0; nt < 4; nt++) {
            float v = 0.f;
#pragma unroll
            for (int mt = 0; mt < 2; mt++)
#pragma unroll
                for (int r = 0; r < 4; r++)
                    v = fmaxf(v, acc[mt * 4 + nt][r]);
            v = fmaxf(v, __shfl_xor(v, 16));
            v = fmaxf(v, __shfl_xor(v, 32));
            if (lane < 16)
                atomicMax((int*)&outF[(size_t)batch * N + n0 + nt * 16 + lane],
                          __float_as_int(v));
        }
        return;
    }
#pragma unroll
    for (int mt = 0; mt < 2; mt++)
#pragma unroll
        for (int nt = 0; nt < 4; nt++)
#pragma unroll
            for (int r = 0; r < 4; r++) {
                const int m = m0 + mh * 32 + mt * 16 + lq * 4 + r;
                const int n = n0 + nt * 16 + lr;
                float v = fmaxf(acc[mt * 4 + nt][r], 0.f);
                short h, l;
                f2bfpair(v, h, l);
                outH[(size_t)m * N + n] = h;
                outL[(size_t)m * N + n] = l;
            }
}

// ---------------------------------------------------------------------------
// FC layer: grid (O/(4*OPW), B), block 256.
// ---------------------------------------------------------------------------
template<int K, int OPW, int ACT>
__global__ __launch_bounds__(256) void fc_kernel(
    const float* __restrict__ in, const float* __restrict__ w,
    const float* __restrict__ bias, float* __restrict__ out, const int O) {
    const int batch = blockIdx.y;
    const int t = threadIdx.x, lane = t & 63, wv = t >> 6;
    __shared__ float f[K];
    for (int j = t; j < K; j += 256) f[j] = in[batch * K + j];
    __syncthreads();
    const int o0 = blockIdx.x * (4 * OPW) + wv * OPW;
#pragma unroll
    for (int i = 0; i < OPW; i++) {
        const int o = o0 + i;
        const float* wr = w + (size_t)o * K;
        float a = 0.f;
#pragma unroll
        for (int c = lane; c < K; c += 64) a = fmaf(wr[c], f[c], a);
#pragma unroll
        for (int off = 32; off > 0; off >>= 1) a += __shfl_xor(a, off);
        if (lane == 0) {
            float v = a + bias[o];
            out[batch * O + o] = ACT ? fmaxf(v, 0.f) : v;
        }
    }
}

// fc3 (256->40) + softmax fused; one block per batch.
__global__ __launch_bounds__(256) void fc3_softmax_kernel(
    const float* __restrict__ in, const float* __restrict__ w3,
    const float* __restrict__ b3, float* __restrict__ out) {
    const int b = blockIdx.x, t = threadIdx.x, lane = t & 63, wv = t >> 6;
    __shared__ float f[256];
    __shared__ float lg[40];
    f[t] = in[b * 256 + t];
    __syncthreads();
#pragma unroll
    for (int i = 0; i < 10; i++) {
        const int o = wv * 10 + i;
        const float* wr = w3 + (size_t)o * 256;
        float a = 0.f;
#pragma unroll
        for (int c = lane; c < 256; c += 64) a = fmaf(wr[c], f[c], a);
#pragma unroll
        for (int off = 32; off > 0; off >>= 1) a += __shfl_xor(a, off);
        if (lane == 0) lg[o] = a + b3[o];
    }
    __syncthreads();
    if (t < 64) {
        float v = (t < 40) ? lg[t] : -INFINITY;
        float m = v;
#pragma unroll
        for (int off = 32; off > 0; off >>= 1) m = fmaxf(m, __shfl_xor(m, off));
        float e = (t < 40) ? expf(v - m) : 0.f;
        float s = e;
#pragma unroll
        for (int off = 32; off > 0; off >>= 1) s += __shfl_xor(s, off);
        if (t < 40) out[b * 40 + t] = e / s;
    }
}

// ---------------------------------------------------------------------------
extern "C" void kernel_launch(void* const* d_in, const int* in_sizes, int n_in,
                              void* d_out, int out_size, void* d_ws, size_t ws_size,
                              hipStream_t stream) {
    (void)in_sizes; (void)n_in; (void)out_size; (void)ws_size;
    const float* x      = (const float*)d_in[0];
    const float* sa1w0  = (const float*)d_in[1];
    const float* sa1b0  = (const float*)d_in[2];
    const float* sa1w1  = (const float*)d_in[3];
    const float* sa1b1  = (const float*)d_in[4];
    const float* sa1w2  = (const float*)d_in[5];
    const float* sa1b2  = (const float*)d_in[6];
    const float* sa2w0  = (const float*)d_in[7];
    const float* sa2b0  = (const float*)d_in[8];
    const float* sa2w1  = (const float*)d_in[9];
    const float* sa2b1  = (const float*)d_in[10];
    const float* sa2w2  = (const float*)d_in[11];
    const float* sa2b2  = (const float*)d_in[12];
    const float* sa3w0  = (const float*)d_in[13];
    const float* sa3b0  = (const float*)d_in[14];
    const float* sa3w1  = (const float*)d_in[15];
    const float* sa3b1  = (const float*)d_in[16];
    const float* sa3w2  = (const float*)d_in[17];
    const float* sa3b2  = (const float*)d_in[18];
    const float* fc1w   = (const float*)d_in[19];
    const float* fc1b   = (const float*)d_in[20];
    const float* fc2w   = (const float*)d_in[21];
    const float* fc2b   = (const float*)d_in[22];
    const float* fc3w   = (const float*)d_in[23];
    const float* fc3b   = (const float*)d_in[24];
    float* outp = (float*)d_out;

    char* ws = (char*)d_ws;
    size_t off = 0;
    auto alloc = [&](size_t bytes) {
        void* p = ws + off;
        off += (bytes + 255) & ~(size_t)255;
        return p;
    };
    float* nxyz1   = (float*)alloc((size_t)B_ * 512 * 3 * 4);
    QPub*  qpub    = (QPub*) alloc((size_t)B_ * 512 * sizeof(QPub));
    int*   idx1    = (int*)  alloc((size_t)B_ * 512 * 32 * 4);
    short* feat1h  = (short*)alloc((size_t)B_ * 512 * 128 * 2);
    short* feat1l  = (short*)alloc((size_t)B_ * 512 * 128 * 2);
    float* nxyz2   = (float*)alloc((size_t)B_ * 128 * 3 * 4);
    int*   idx2    = (int*)  alloc((size_t)B_ * 128 * 64 * 4);
    short* a3h     = (short*)alloc((size_t)4096 * 288 * 2);
    short* a3l     = (short*)alloc((size_t)4096 * 288 * 2);
    short* h3ah    = (short*)alloc((size_t)4096 * 256 * 2);
    short* h3al    = (short*)alloc((size_t)4096 * 256 * 2);
    short* h3bh    = (short*)alloc((size_t)4096 * 512 * 2);
    short* h3bl    = (short*)alloc((size_t)4096 * 512 * 2);
    float* gfeat   = (float*)alloc((size_t)B_ * 1024 * 4);
    float* h1      = (float*)alloc((size_t)B_ * 512 * 4);
    float* h2      = (float*)alloc((size_t)B_ * 256 * 4);
    // split-bf16 weight planes
    short* w1h_s1 = (short*)alloc((size_t)64 * 64 * 2);
    short* w1l_s1 = (short*)alloc((size_t)64 * 64 * 2);
    short* w2h_s1 = (short*)alloc((size_t)128 * 64 * 2);
    short* w2l_s1 = (short*)alloc((size_t)128 * 64 * 2);
    short* w0h_s2 = (short*)alloc((size_t)128 * 160 * 2);
    short* w0l_s2 = (short*)alloc((size_t)128 * 160 * 2);
    short* w1h_s2 = (short*)alloc((size_t)128 * 128 * 2);
    short* w1l_s2 = (short*)alloc((size_t)128 * 128 * 2);
    short* w2h_s2 = (short*)alloc((size_t)256 * 128 * 2);
    short* w2l_s2 = (short*)alloc((size_t)256 * 128 * 2);
    short* w0h_s3 = (short*)alloc((size_t)256 * 288 * 2);
    short* w0l_s3 = (short*)alloc((size_t)256 * 288 * 2);
    short* w1h_s3 = (short*)alloc((size_t)512 * 256 * 2);
    short* w1l_s3 = (short*)alloc((size_t)512 * 256 * 2);
    short* w2h_s3 = (short*)alloc((size_t)1024 * 512 * 2);
    short* w2l_s3 = (short*)alloc((size_t)1024 * 512 * 2);

    // re-poison safety: seq fields must start at 0 each launch
    hipMemsetAsync(qpub, 0, (size_t)B_ * 512 * sizeof(QPub), stream);

    // K1: merged {fps1 producer + wprep + ballquery1 consumers}
    {
        WDescs W;
        const float* srcs[8] = {sa1w1, sa1w2, sa2w0, sa2w1, sa2w2, sa3w0, sa3w1, sa3w2};
        short* dhs[8] = {w1h_s1, w2h_s1, w0h_s2, w1h_s2, w2h_s2, w0h_s3, w1h_s3, w2h_s3};
        short* dls[8] = {w1l_s1, w2l_s1, w0l_s2, w1l_s2, w2l_s2, w0l_s3, w1l_s3, w2l_s3};
        int Rs[8]  = {64, 128, 128, 128, 256, 256, 512, 1024};
        int Cs[8]  = {64, 64, 131, 128, 128, 259, 256, 512};
        int Cps[8] = {64, 64, 160, 128, 128, 288, 256, 512};
        int blk = 0;
        for (int k = 0; k < 8; k++) {
            W.d[k] = {srcs[k], dhs[k], dls[k], Rs[k], Cs[k], Cps[k], blk,
                      (k == 2) ? 1 : 0};
            blk += (Rs[k] * Cps[k] + 255) / 256;
        }
        W.gfeat = gfeat;
        W.gblk0 = blk;
        W.gtotal = B_ * 1024;
        int witems = blk + (B_ * 1024 + 255) / 256;
        fps_bq1_kernel<4096, 512, 256, B_, 736>
            <<<B_ + 736, 256, 0, stream>>>(
                x, nxyz1, idx1, 0.04f, qpub, W, witems);
    }

    // K2: {fps2 (first, overlapped) + sa1}
    fps2_sa1_kernel<B_, 512, 128><<<B_ + 8192, 256, 0, stream>>>(
        x, nxyz1, idx1, sa1w0, sa1b0,
        w1h_s1, w1l_s1, sa1b1, w2h_s1, w2l_s1, sa1b2, feat1h, feat1l,
        nxyz2);
    // K3: ballquery2 (needs nxyz2)
    bq2_kernel<<<1024, 256, 0, stream>>>(nxyz1, nxyz2, idx2, 0.16f);
    // SA2
    sa2_mfma_kernel<<<B_ * 128, 256, 0, stream>>>(
        nxyz1, feat1h, feat1l, nxyz2, idx2,
        w0h_s2, w0l_s2, sa2b0, w1h_s2, w1l_s2, sa2b1, w2h_s2, w2l_s2, sa2b2,
        a3h, a3l);
    // SA3 (group-all): 3 MFMA GEMMs on planes; gemm3 fuses the maxpool
    mfma_gemm_kernel<1><<<dim3(2, 64), 256, 0, stream>>>(
        a3h, a3l, 288, w0h_s3, w0l_s3, sa3b0, nullptr, h3ah, h3al, 256);
    mfma_gemm_kernel<1><<<dim3(4, 64), 256, 0, stream>>>(
        h3ah, h3al, 256, w1h_s3, w1l_s3, sa3b1, nullptr, h3bh, h3bl, 512);
    mfma_gemm_kernel<2><<<dim3(8, 64), 256, 0, stream>>>(
        h3bh, h3bl, 512, w2h_s3, w2l_s3, sa3b2, gfeat, nullptr, nullptr, 1024);
    // FC head: fc1 (1024->512), fc2 (512->256), fc3+softmax
    fc_kernel<1024, 16, 1><<<dim3(8, B_), 256, 0, stream>>>(
        gfeat, fc1w, fc1b, h1, 512);
    fc_kernel<512, 16, 1><<<dim3(4, B_), 256, 0, stream>>>(
        h1, fc2w, fc2b, h2, 256);
    fc3_softmax_kernel<<<B_, 256, 0, stream>>>(h2, fc3w, fc3b, outp);
}

// Round 8
// 928.833 us; speedup vs baseline: 1.3228x; 1.3228x over previous
//
#include <hip/hip_runtime.h>
#include <math.h>

#define B_ 32
#define N_ 4096

typedef __attribute__((ext_vector_type(8))) short short8;
typedef __attribute__((ext_vector_type(4))) float f32x4;
typedef __attribute__((ext_vector_type(2))) float v2f;
typedef __attribute__((ext_vector_type(2))) unsigned u32x2;
typedef __attribute__((ext_vector_type(2))) unsigned long long u64x2;

// fp32 -> bf16 round-to-nearest-even, and split x = hi + lo (both bf16).
__device__ __forceinline__ unsigned short f2bf(float f) {
    unsigned u = __float_as_uint(f);
    unsigned r = 0x7FFFu + ((u >> 16) & 1u);
    return (unsigned short)((u + r) >> 16);
}
__device__ __forceinline__ float bf2f(unsigned short h) {
    return __uint_as_float(((unsigned)h) << 16);
}
__device__ __forceinline__ void f2bfpair(float v, short& h, short& l) {
    unsigned short hh = f2bf(v);
    h = (short)hh;
    l = (short)f2bf(v - bf2f(hh));
}

// ---------------------------------------------------------------------------
// Packed argmax key = (float_bits(dist)+BIAS << 32) | ~idx.
// BIAS = 0x3F800000. dist < 3 always (coords in [0,1)), so the biased high
// word lies in [0x3F800000, 0x7FC00000]: sign 0, double-exponent field (bits
// 62..52 of the u64) never 0 and never all-ones -> every key is a NORMAL
// POSITIVE double. For such values f64 compare == u64 compare of the bit
// pattern, so v_max_f64 (1 instr) replaces cmp_u64+2*cndmask (3 instr) while
// remaining bit-exact: max dist wins, min idx on tie (low word = ~idx),
// identical to reference first-index argmax. Keys > 0, so max with 0.0
// (DPP bound_ctrl fill / accumulator init) is identity.
// Key construction goes through a u32x2 bit-cast so the compiler just
// places {lo, hi} in a register pair — no v_lshlrev_b64/v_or_b32 sequences.
// ---------------------------------------------------------------------------
#define KEY_BIAS 0x3F800000u

__device__ __forceinline__ double mk_key(unsigned hi, unsigned lo) {
    u32x2 p;
    p[0] = lo;
    p[1] = hi;
    return __builtin_bit_cast(double, p);
}

__device__ __forceinline__ unsigned long long u64max(unsigned long long a,
                                                     unsigned long long b) {
    return a > b ? a : b;
}
template<int CTRL>
__device__ __forceinline__ double dpp_dbl(double k) {
    unsigned long long u = (unsigned long long)__double_as_longlong(k);
    int lo = __builtin_amdgcn_mov_dpp((int)(unsigned)u, CTRL, 0xf, 0xf, true);
    int hi = __builtin_amdgcn_mov_dpp((int)(unsigned)(u >> 32), CTRL, 0xf, 0xf, true);
    unsigned long long r = ((unsigned long long)(unsigned)hi << 32) | (unsigned)lo;
    return __longlong_as_double((long long)r);
}
// Leader-only result in LANE 63, pure DPP: row_ror reduce within rows, then
// row_bcast15/31 across rows.
__device__ __forceinline__ double wave_argmax_dbl_leader(double key) {
    key = fmax(key, dpp_dbl<0x128>(key));     // row_ror:8
    key = fmax(key, dpp_dbl<0x124>(key));     // row_ror:4
    key = fmax(key, dpp_dbl<0x122>(key));     // row_ror:2
    key = fmax(key, dpp_dbl<0x121>(key));     // row_ror:1
    key = fmax(key, dpp_dbl<0x142>(key));     // row_bcast15
    key = fmax(key, dpp_dbl<0x143>(key));     // row_bcast31 -> lane 63
    return key;
}

// ---------------------------------------------------------------------------
// Weight prep (device body): split 8 fp32 [R][C] mats into bf16 hi/lo
// [R][Cp]. perm=1 (sa2w0): column remap feat-first to match sa2's
// activation layout. Tail blocks (>= gblk0) zero gfeat for the fused-maxpool
// atomics. Merged into the fps launch as tail blocks — fps only occupies
// 32 CUs, wprep fills the idle 224.
// ---------------------------------------------------------------------------
struct WDesc { const float* src; short* dh; short* dl; int R, C, Cp, blk0, perm; };
struct WDescs { WDesc d[8]; float* gfeat; int gblk0, gtotal; };

__device__ __forceinline__ void wprep_body(const WDescs& W, int blk, int tid) {
    if (blk >= W.gblk0) {
        const int i = (blk - W.gblk0) * 256 + tid;
        if (i < W.gtotal) W.gfeat[i] = 0.f;
        return;
    }
    int di = 0;
#pragma unroll
    for (int k = 1; k < 8; k++) di = (blk >= W.d[k].blk0) ? k : di;
    const WDesc D = W.d[di];
    const int i = (blk - D.blk0) * 256 + tid;
    if (i >= D.R * D.Cp) return;
    const int r = i / D.Cp, c = i % D.Cp;
    int cs;
    if (D.perm) cs = (c < 128) ? c + 3 : (c < 131 ? c - 128 : -1);
    else        cs = (c < D.C) ? c : -1;
    float v = (cs >= 0) ? D.src[r * D.C + cs] : 0.f;
    short h, l;
    f2bfpair(v, h, l);
    D.dh[i] = h; D.dl[i] = l;
}

// ---------------------------------------------------------------------------
// FPS stage 1 + merged weight prep: blocks [0, FPSB) run fps (one per
// batch, exact fp32 math — index-critical); blocks >= FPSB run wprep.
// Point pairs as <2 x float> (v_pk_* full rate), min-update as one
// v_pk_min_f32 (elementwise_min — bit-identical to two fminf), key max via
// v_max_f64, 4 independent key accumulators, LDS-buffered output flushed
// at the end.
// ---------------------------------------------------------------------------
template<int N, int NPOINT, int NT, int FPSB>
__global__ __launch_bounds__(NT, 1) void fps_wprep_kernel(
    const float* __restrict__ xyz, float* __restrict__ outXyz, WDescs W) {
#pragma clang fp contract(off)
    const int t = threadIdx.x;
    if (blockIdx.x >= FPSB) {
        wprep_body(W, blockIdx.x - FPSB, t);
        return;
    }
    const int b = blockIdx.x;
    constexpr int PPT = N / NT;
    constexpr int PP2 = PPT / 2;
    constexpr int NW = (NT + 63) / 64;    // == 4
    __shared__ float ps[N][4];
    __shared__ __align__(16) double red[2][NW];
    __shared__ float outBuf[NPOINT * 3];
    const float* base = xyz + (size_t)b * N * 3;
    for (int j = t; j < N; j += NT) {
        ps[j][0] = base[j * 3 + 0];
        ps[j][1] = base[j * 3 + 1];
        ps[j][2] = base[j * 3 + 2];
    }
    __syncthreads();
    v2f px2[PP2], py2[PP2], pz2[PP2], mn2[PP2];
    unsigned nA[PP2], nB[PP2];
#pragma unroll
    for (int j = 0; j < PP2; j++) {
        const int p0 = t + (2 * j) * NT;
        const int p1 = t + (2 * j + 1) * NT;
        f32x4 a = *(const f32x4*)&ps[p0][0];
        f32x4 c = *(const f32x4*)&ps[p1][0];
        px2[j] = (v2f){a[0], c[0]};
        py2[j] = (v2f){a[1], c[1]};
        pz2[j] = (v2f){a[2], c[2]};
        mn2[j] = (v2f){1e10f, 1e10f};
        nA[j] = ~(unsigned)p0;
        nB[j] = ~(unsigned)p1;
    }
#pragma unroll
    for (int j = 0; j < PP2; j++)
        asm volatile("" : "+v"(px2[j]), "+v"(py2[j]), "+v"(pz2[j]));
    float lx = ps[0][0], ly = ps[0][1], lz = ps[0][2];
    if (t == 0) {
        outBuf[0] = lx; outBuf[1] = ly; outBuf[2] = lz;
    }
    for (int it = 1; it < NPOINT; it++) {
        const v2f lx2 = (v2f){lx, lx};
        const v2f ly2 = (v2f){ly, ly};
        const v2f lz2 = (v2f){lz, lz};
        double k0 = 0.0, k1 = 0.0, k2 = 0.0, k3 = 0.0;
#pragma unroll
        for (int j = 0; j < PP2; j++) {
            v2f dx = px2[j] - lx2;
            v2f dy = py2[j] - ly2;
            v2f dz = pz2[j] - lz2;
            v2f t0 = dx * dx, t1 = dy * dy, t2 = dz * dz;
            v2f d2 = (t0 + t1) + t2;
            v2f m = __builtin_elementwise_min(mn2[j], d2);
            mn2[j] = m;
            double da = mk_key(__float_as_uint(m[0]) + KEY_BIAS, nA[j]);
            double db = mk_key(__float_as_uint(m[1]) + KEY_BIAS, nB[j]);
            if (j & 1) { k2 = fmax(k2, da); k3 = fmax(k3, db); }
            else       { k0 = fmax(k0, da); k1 = fmax(k1, db); }
        }
        double key = fmax(fmax(k0, k1), fmax(k2, k3));
        key = wave_argmax_dbl_leader(key);
        const int par = it & 1;
        if ((t & 63) == 63) red[par][t >> 6] = key;
        __syncthreads();
        u64x2 r01 = *(const u64x2*)&red[par][0];
        u64x2 r23 = *(const u64x2*)&red[par][2];
        double b0 = __longlong_as_double((long long)r01[0]);
        double b1 = __longlong_as_double((long long)r01[1]);
        double b2 = __longlong_as_double((long long)r23[0]);
        double b3 = __longlong_as_double((long long)r23[1]);
        double best = fmax(fmax(b0, b1), fmax(b2, b3));
        const int fi = (int)(~(unsigned)(unsigned long long)__double_as_longlong(best));
        f32x4 c4 = *(const f32x4*)&ps[fi][0];
        lx = c4[0]; ly = c4[1]; lz = c4[2];
        if (t == 0) {
            outBuf[it * 3 + 0] = lx;
            outBuf[it * 3 + 1] = ly;
            outBuf[it * 3 + 2] = lz;
        }
    }
    __syncthreads();
    float* dst = outXyz + (size_t)b * NPOINT * 3;
    for (int j = t; j < NPOINT * 3; j += NT) dst[j] = outBuf[j];
}

// ---------------------------------------------------------------------------
// Ball-query body: wave-per-query (ballot/mbcnt), exact fp32 math.
// ---------------------------------------------------------------------------
template<int N, int NS>
__device__ __forceinline__ void ballquery_body(
    const float* __restrict__ xyz, const float* __restrict__ newXyz,
    int* __restrict__ outIdx, int S, float r2, int qid, int lane) {
#pragma clang fp contract(off)
    const int b = qid / S;
    const float* q = newXyz + (size_t)qid * 3;
    const float qx = q[0], qy = q[1], qz = q[2];
    const float qn = (qx * qx + qy * qy) + qz * qz;
    const float* base = xyz + (size_t)b * N * 3;
    int* dst = outIdx + (size_t)qid * NS;
    int cnt = 0, first = 0;
    for (int p0 = 0; p0 < N; p0 += 64) {
        const int p = p0 + lane;
        const float x = base[p * 3 + 0];
        const float y = base[p * 3 + 1];
        const float z = base[p * 3 + 2];
        const float pn = (x * x + y * y) + z * z;
        const float dot = (qx * x + qy * y) + qz * z;
        const float sqd = (qn + pn) - 2.0f * dot;
        const unsigned long long mask = __ballot(sqd <= r2);
        if (mask) {
            if (cnt == 0) first = p0 + __ffsll((unsigned long long)mask) - 1;
            const int prefix = __builtin_amdgcn_mbcnt_hi(
                (unsigned)(mask >> 32),
                __builtin_amdgcn_mbcnt_lo((unsigned)mask, 0));
            const bool in = (mask >> lane) & 1ull;
            const int pos = cnt + prefix;
            if (in && pos < NS) dst[pos] = p;
            cnt += __popcll(mask);
            if (cnt >= NS) break;
        }
    }
    for (int i = cnt + lane; i < NS; i += 64) dst[i] = first;
}

// ---------------------------------------------------------------------------
// Merged launch: blocks [0, FPB) = fps stage 2 (nxyz1 -> nxyz2), blocks
// [FPB, FPB+BQB) = ballquery1 (x -> idx1). fps2 blocks carry the serial
// 128-iter tail, so they get the LOWEST block IDs — dispatched first and
// fully overlapped with bq1. fps2 inner loop uses the same pk-pair +
// pk_min + v_max_f64 biased-key scheme as fps1 (bit-exact). fps2
// reduction: leader DPP chain + single shfl of the low word (fi only
// needs lo 32 bits). Per-iter global stores are fire-and-forget (single
// wave, no barrier in the loop).
// ---------------------------------------------------------------------------
template<int FPB, int BQB, int NQ, int NS, int SQ, int NF, int NPF>
__global__ __launch_bounds__(256) void bq_fps_kernel(
    const float* __restrict__ xyzQ, const float* __restrict__ newXyzQ,
    int* __restrict__ outIdxQ, float r2,
    const float* __restrict__ xyzF, float* __restrict__ outXyzF) {
#pragma clang fp contract(off)
    const int t = threadIdx.x;
    const int lane = t & 63, wv = t >> 6;
    __shared__ float ps[NF][4];
    if (blockIdx.x >= FPB) {
        ballquery_body<NQ, NS>(xyzQ, newXyzQ, outIdxQ, SQ, r2,
                               (blockIdx.x - FPB) * 4 + wv, lane);
        return;
    }
    // ---- fps2: single-wave serial FPS over NF points ----
    const int b = blockIdx.x;
    const float* base = xyzF + (size_t)b * NF * 3;
    for (int j = t; j < NF; j += 256) {
        ps[j][0] = base[j * 3 + 0];
        ps[j][1] = base[j * 3 + 1];
        ps[j][2] = base[j * 3 + 2];
    }
    __syncthreads();
    if (t >= 64) return;
    constexpr int PPT = NF / 64;
    constexpr int PP2 = PPT / 2;
    v2f px2[PP2], py2[PP2], pz2[PP2], mn2[PP2];
    unsigned nA[PP2], nB[PP2];
#pragma unroll
    for (int j = 0; j < PP2; j++) {
        const int p0 = t + (2 * j) * 64;
        const int p1 = t + (2 * j + 1) * 64;
        f32x4 a = *(const f32x4*)&ps[p0][0];
        f32x4 c = *(const f32x4*)&ps[p1][0];
        px2[j] = (v2f){a[0], c[0]};
        py2[j] = (v2f){a[1], c[1]};
        pz2[j] = (v2f){a[2], c[2]};
        mn2[j] = (v2f){1e10f, 1e10f};
        nA[j] = ~(unsigned)p0;
        nB[j] = ~(unsigned)p1;
    }
    float lx = ps[0][0], ly = ps[0][1], lz = ps[0][2];
    if (t == 0) {
        outXyzF[(size_t)b * NPF * 3 + 0] = lx;
        outXyzF[(size_t)b * NPF * 3 + 1] = ly;
        outXyzF[(size_t)b * NPF * 3 + 2] = lz;
    }
    for (int it = 1; it < NPF; it++) {
        const v2f lx2 = (v2f){lx, lx};
        const v2f ly2 = (v2f){ly, ly};
        const v2f lz2 = (v2f){lz, lz};
        double k0 = 0.0, k1 = 0.0;
#pragma unroll
        for (int j = 0; j < PP2; j++) {
            v2f dx = px2[j] - lx2;
            v2f dy = py2[j] - ly2;
            v2f dz = pz2[j] - lz2;
            v2f t0 = dx * dx, t1 = dy * dy, t2 = dz * dz;
            v2f d2 = (t0 + t1) + t2;
            v2f m = __builtin_elementwise_min(mn2[j], d2);
            mn2[j] = m;
            double da = mk_key(__float_as_uint(m[0]) + KEY_BIAS, nA[j]);
            double db = mk_key(__float_as_uint(m[1]) + KEY_BIAS, nB[j]);
            k0 = fmax(k0, da);
            k1 = fmax(k1, db);
        }
        double key = fmax(k0, k1);
        key = wave_argmax_dbl_leader(key);
        const int lo = __shfl(
            (int)(unsigned)(unsigned long long)__double_as_longlong(key), 63);
        const int fi = (int)(~(unsigned)lo);
        f32x4 c4 = *(const f32x4*)&ps[fi][0];
        lx = c4[0]; ly = c4[1]; lz = c4[2];
        if (t == 0) {
            outXyzF[((size_t)b * NPF + it) * 3 + 0] = lx;
            outXyzF[((size_t)b * NPF + it) * 3 + 1] = ly;
            outXyzF[((size_t)b * NPF + it) * 3 + 2] = lz;
        }
    }
}

// ---------------------------------------------------------------------------
// MFMA helpers (verified gfx950 16x16x32 bf16 layouts).
// Split fp32 = hi+lo bf16: D += Ah*Bh + Ah*Bl + Al*Bh
// ---------------------------------------------------------------------------
template<int NT, int KS>
__device__ __forceinline__ void mfma_layer(
    const short* Aph, const short* Apl, const int sA,
    const short* __restrict__ Wph, const short* __restrict__ Wpl, const int sW,
    f32x4* acc, const int n0, const int mh, const int lr, const int lq) {
#pragma unroll
    for (int ks = 0; ks < KS; ks++) {
        const int ka = ks * 32 + lq * 8;
        short8 a_h[2], a_l[2];
#pragma unroll
        for (int mt = 0; mt < 2; mt++) {
            const int m = (mh * 2 + mt) * 16 + lr;
            a_h[mt] = *(const short8*)(Aph + m * sA + ka);
            a_l[mt] = *(const short8*)(Apl + m * sA + ka);
        }
#pragma unroll
        for (int nt = 0; nt < NT; nt++) {
            const int n = n0 + nt * 16 + lr;
            short8 b_h = *(const short8*)(Wph + (size_t)n * sW + ka);
            short8 b_l = *(const short8*)(Wpl + (size_t)n * sW + ka);
#pragma unroll
            for (int mt = 0; mt < 2; mt++) {
                f32x4 c = acc[mt * NT + nt];
                c = __builtin_amdgcn_mfma_f32_16x16x32_bf16(a_h[mt], b_h, c, 0, 0, 0);
                c = __builtin_amdgcn_mfma_f32_16x16x32_bf16(a_h[mt], b_l, c, 0, 0, 0);
                c = __builtin_amdgcn_mfma_f32_16x16x32_bf16(a_l[mt], b_h, c, 0, 0, 0);
                acc[mt * NT + nt] = c;
            }
        }
    }
}

template<int NT>
__device__ __forceinline__ void init_bias(f32x4* acc, const float* __restrict__ bias,
                                          const int n0, const int lr) {
#pragma unroll
    for (int nt = 0; nt < NT; nt++) {
        float bv = bias[n0 + nt * 16 + lr];
        f32x4 c = {bv, bv, bv, bv};
        acc[0 * NT + nt] = c;
        acc[1 * NT + nt] = c;
    }
}

template<int NT>
__device__ __forceinline__ void store_split(
    const f32x4* acc, short* Hp, short* Lp, const int stride,
    const int n0, const int mh, const int lr, const int lq) {
#pragma unroll
    for (int mt = 0; mt < 2; mt++)
#pragma unroll
        for (int nt = 0; nt < NT; nt++)
#pragma unroll
            for (int r = 0; r < 4; r++) {
                float v = fmaxf(acc[mt * NT + nt][r], 0.f);
                short h, l;
                f2bfpair(v, h, l);
                const int m = (mh * 2 + mt) * 16 + lq * 4 + r;
                const int n = n0 + nt * 16 + lr;
                Hp[m * stride + n] = h;
                Lp[m * stride + n] = l;
            }
}

// ---------------------------------------------------------------------------
// SA1 MFMA (+ merged ballquery2 blocks): blocks [0, BQ2B) run bq2 first
// (low IDs overlap them with sa1 instead of serializing as a tail);
// blocks >= BQ2B run sa1.
// ---------------------------------------------------------------------------
#define T1 72
template<int BQ2B>
__global__ __launch_bounds__(256) void sa1_bq2_kernel(
    const float* __restrict__ x, const float* __restrict__ nxyz1,
    const int* __restrict__ idx,
    const float* __restrict__ w0, const float* __restrict__ b0,
    const short* __restrict__ w1h, const short* __restrict__ w1l,
    const float* __restrict__ b1,
    const short* __restrict__ w2h, const short* __restrict__ w2l,
    const float* __restrict__ b2,
    short* __restrict__ feat1h, short* __restrict__ feat1l,
    const float* __restrict__ nxyz2, int* __restrict__ idx2, float r2q) {
    const int t = threadIdx.x;
    const int lane = t & 63, wv = t >> 6;
    if (blockIdx.x < BQ2B) {   // ballquery2: N=512, NS=64, S=128
        ballquery_body<512, 64>(nxyz1, nxyz2, idx2, 128, r2q,
                                blockIdx.x * 4 + wv, lane);
        return;
    }
    const int g0 = (blockIdx.x - BQ2B) * 2;
    const int b = g0 >> 9;
    const int lr = lane & 15, lq = lane >> 4;
    const int mh = wv & 1, nh = wv >> 1;
    __shared__ float gx[64][4];
    __shared__ short H1h[64 * T1], H1l[64 * T1];
    __shared__ short H2h[64 * T1], H2l[64 * T1];
    if (t < 64) {
        int g = g0 + (t >> 5);
        int id = idx[(size_t)g * 32 + (t & 31)];
        const float* pp = x + ((size_t)b * N_ + id) * 3;
        const float* cc = nxyz1 + (size_t)g * 3;
        gx[t][0] = pp[0] - cc[0];
        gx[t][1] = pp[1] - cc[1];
        gx[t][2] = pp[2] - cc[2];
    }
    __syncthreads();
    {   // layer1 K=3 via VALU
        const int m = t >> 2, oc = (t & 3) * 16;
        float a0 = gx[m][0], a1 = gx[m][1], a2 = gx[m][2];
        short8 hv0, hv1, lv0, lv1;
#pragma unroll
        for (int i = 0; i < 16; i++) {
            int o = oc + i;
            float v = fmaf(w0[o * 3 + 0], a0,
                      fmaf(w0[o * 3 + 1], a1,
                      fmaf(w0[o * 3 + 2], a2, b0[o])));
            v = fmaxf(v, 0.f);
            short h, l;
            f2bfpair(v, h, l);
            if (i < 8) { hv0[i] = h; lv0[i] = l; }
            else       { hv1[i - 8] = h; lv1[i - 8] = l; }
        }
        *(short8*)&H1h[m * T1 + oc]     = hv0;
        *(short8*)&H1h[m * T1 + oc + 8] = hv1;
        *(short8*)&H1l[m * T1 + oc]     = lv0;
        *(short8*)&H1l[m * T1 + oc + 8] = lv1;
    }
    __syncthreads();
    {   // layer2: K=64, N=64
        f32x4 acc[4];
        init_bias<2>(acc, b1, nh * 32, lr);
        mfma_layer<2, 2>(H1h, H1l, T1, w1h, w1l, 64, acc, nh * 32, mh, lr, lq);
        store_split<2>(acc, H2h, H2l, T1, nh * 32, mh, lr, lq);
    }
    __syncthreads();
    {   // layer3: K=64, N=128 + per-group max, split output
        f32x4 acc[8];
        init_bias<4>(acc, b2, nh * 64, lr);
        mfma_layer<4, 2>(H2h, H2l, T1, w2h, w2l, 64, acc, nh * 64, mh, lr, lq);
#pragma unroll
        for (int nt = 0; nt < 4; nt++) {
            float v = 0.f;
#pragma unroll
            for (int mt = 0; mt < 2; mt++)
#pragma unroll
                for (int r = 0; r < 4; r++)
                    v = fmaxf(v, acc[mt * 4 + nt][r]);
            v = fmaxf(v, __shfl_xor(v, 16));
            v = fmaxf(v, __shfl_xor(v, 32));
            if (lane < 16) {
                short h, l;
                f2bfpair(v, h, l);
                size_t o = (size_t)(g0 + mh) * 128 + nh * 64 + nt * 16 + lane;
                feat1h[o] = h;
                feat1l[o] = l;
            }
        }
    }
}

// ---------------------------------------------------------------------------
// SA2 MFMA: consumes feat1 planes (feat-first layout), outputs a3 planes.
// ---------------------------------------------------------------------------
#define S1 168
#define S2 136
__global__ __launch_bounds__(256) void sa2_mfma_kernel(
    const float* __restrict__ xyz1,
    const short* __restrict__ feat1h, const short* __restrict__ feat1l,
    const float* __restrict__ newXyz, const int* __restrict__ idx,
    const short* __restrict__ w0h, const short* __restrict__ w0l,
    const float* __restrict__ b0,
    const short* __restrict__ w1h, const short* __restrict__ w1l,
    const float* __restrict__ b1,
    const short* __restrict__ w2h, const short* __restrict__ w2l,
    const float* __restrict__ b2,
    short* __restrict__ a3h, short* __restrict__ a3l) {
    const int g = blockIdx.x;
    const int b = g >> 7;
    const int t = threadIdx.x;
    const int lane = t & 63, wv = t >> 6;
    const int lr = lane & 15, lq = lane >> 4;
    const int mh = wv & 1, nh = wv >> 1;
    __shared__ short Ah[64 * S1], Al[64 * S1];
    __shared__ short Hh[64 * S2], Hl[64 * S2];
    __shared__ float pmax[2][256];
    __shared__ int ids[64];
    if (t < 64) ids[t] = idx[(size_t)g * 64 + t];
    __syncthreads();
    {   // gather: feat cols 0..127 via b128 plane copies; xyz at 128..130
        const int m = t >> 2, q = t & 3;
        const int id = ids[m];
        const size_t frow = ((size_t)b * 512 + id) * 128;
#pragma unroll
        for (int c8 = 0; c8 < 4; c8++) {
            const int k = q * 32 + c8 * 8;
            *(short8*)&Ah[m * S1 + k] = *(const short8*)(feat1h + frow + k);
            *(short8*)&Al[m * S1 + k] = *(const short8*)(feat1l + frow + k);
        }
        if (t < 64) {
            const int id2 = ids[t];
            short8 zz = {0, 0, 0, 0, 0, 0, 0, 0};
            *(short8*)&Ah[t * S1 + 128] = zz;
            *(short8*)&Ah[t * S1 + 136] = zz;
            *(short8*)&Ah[t * S1 + 144] = zz;
            *(short8*)&Ah[t * S1 + 152] = zz;
            *(short8*)&Al[t * S1 + 128] = zz;
            *(short8*)&Al[t * S1 + 136] = zz;
            *(short8*)&Al[t * S1 + 144] = zz;
            *(short8*)&Al[t * S1 + 152] = zz;
            const float* prow = xyz1 + ((size_t)b * 512 + id2) * 3;
            const float* crow = newXyz + (size_t)g * 3;
#pragma unroll
            for (int c = 0; c < 3; c++) {
                short h, l;
                f2bfpair(prow[c] - crow[c], h, l);
                Ah[t * S1 + 128 + c] = h;
                Al[t * S1 + 128 + c] = l;
            }
        }
    }
    __syncthreads();
    {   // layer1: K=160, N=128
        f32x4 acc[8];
        init_bias<4>(acc, b0, nh * 64, lr);
        mfma_layer<4, 5>(Ah, Al, S1, w0h, w0l, 160, acc, nh * 64, mh, lr, lq);
        store_split<4>(acc, Hh, Hl, S2, nh * 64, mh, lr, lq);
    }
    __syncthreads();
    {   // layer2: K=128, N=128
        f32x4 acc[8];
        init_bias<4>(acc, b1, nh * 64, lr);
        mfma_layer<4, 4>(Hh, Hl, S2, w1h, w1l, 128, acc, nh * 64, mh, lr, lq);
        store_split<4>(acc, Ah, Al, S2, nh * 64, mh, lr, lq);
    }
    __syncthreads();
    {   // layer3: K=128, N=256 + max over 64 rows
        f32x4 acc[16];
        init_bias<8>(acc, b2, nh * 128, lr);
        mfma_layer<8, 4>(Ah, Al, S2, w2h, w2l, 128, acc, nh * 128, mh, lr, lq);
#pragma unroll
        for (int nt = 0; nt < 8; nt++) {
            float v = 0.f;
#pragma unroll
            for (int mt = 0; mt < 2; mt++)
#pragma unroll
                for (int r = 0; r < 4; r++)
                    v = fmaxf(v, acc[mt * 8 + nt][r]);
            v = fmaxf(v, __shfl_xor(v, 16));
            v = fmaxf(v, __shfl_xor(v, 32));
            if (lane < 16) pmax[mh][nh * 128 + nt * 16 + lane] = v;
        }
    }
    __syncthreads();
    {   // write a3 row g: col 3+t = feat, cols 0..2 xyz, 259..287 zero
        float v = fmaxf(pmax[0][t], pmax[1][t]);
        short h, l;
        f2bfpair(v, h, l);
        a3h[(size_t)g * 288 + 3 + t] = h;
        a3l[(size_t)g * 288 + 3 + t] = l;
        if (t < 3) {
            f2bfpair(newXyz[(size_t)g * 3 + t], h, l);
            a3h[(size_t)g * 288 + t] = h;
            a3l[(size_t)g * 288 + t] = l;
        }
        if (t >= 227) {
            a3h[(size_t)g * 288 + t + 32] = 0;
            a3l[(size_t)g * 288 + t + 32] = 0;
        }
    }
}

// ---------------------------------------------------------------------------
// MFMA GEMM: A pre-split planes [M][Kp]; weights pre-split planes [N][Kp].
// OUT_MODE 1: relu + split-plane output.
// OUT_MODE 2: relu + per-column block max + atomicMax into gfeat (fused
//   maxpool; values >=0 so int-compare on float bits is order-correct).
// ---------------------------------------------------------------------------
template<int OUT_MODE>
__global__ __launch_bounds__(256) void mfma_gemm_kernel(
    const short* __restrict__ Agh, const short* __restrict__ Agl, const int Kp,
    const short* __restrict__ Wh, const short* __restrict__ Wl,
    const float* __restrict__ bias,
    float* __restrict__ outF, short* __restrict__ outH,
    short* __restrict__ outL, const int N) {
    const int t = threadIdx.x;
    const int lane = t & 63, wv = t >> 6;
    const int lr = lane & 15, lq = lane >> 4;
    const int mh = wv & 1, nh = wv >> 1;
    const int m0 = blockIdx.y * 64;
    const int n0 = blockIdx.x * 128 + nh * 64;
    __shared__ short Ah[64 * 40], Al[64 * 40];
    f32x4 acc[8];
#pragma unroll
    for (int nt = 0; nt < 4; nt++) {
        float bv = bias[n0 + nt * 16 + lr];
        f32x4 c = {bv, bv, bv, bv};
        acc[nt] = c; acc[4 + nt] = c;
    }
    const int srow = t >> 2, sk = (t & 3) * 8;
    for (int kt = 0; kt < Kp; kt += 32) {
        {   // stage A chunk: pure b128 copies (no conversion)
            const size_t src = (size_t)(m0 + srow) * Kp + kt + sk;
            *(short8*)&Ah[srow * 40 + sk] = *(const short8*)(Agh + src);
            *(short8*)&Al[srow * 40 + sk] = *(const short8*)(Agl + src);
        }
        __syncthreads();
        short8 a_h[2], a_l[2];
#pragma unroll
        for (int mt = 0; mt < 2; mt++) {
            const int m = mh * 32 + mt * 16 + lr;
            a_h[mt] = *(const short8*)&Ah[m * 40 + lq * 8];
            a_l[mt] = *(const short8*)&Al[m * 40 + lq * 8];
        }
#pragma unroll
        for (int nt = 0; nt < 4; nt++) {
            const int n = n0 + nt * 16 + lr;
            short8 b_h = *(const short8*)(Wh + (size_t)n * Kp + kt + lq * 8);
            short8 b_l = *(const short8*)(Wl + (size_t)n * Kp + kt + lq * 8);
#pragma unroll
            for (int mt = 0; mt < 2; mt++) {
                f32x4 c = acc[mt * 4 + nt];
                c = __builtin_amdgcn_mfma_f32_16x16x32_bf16(a_h[mt], b_h, c, 0, 0, 0);
                c = __builtin_amdgcn_mfma_f32_16x16x32_bf16(a_h[mt], b_l, c, 0, 0, 0);
                c = __builtin_amdgcn_mfma_f32_16x16x32_bf16(a_l[mt], b_h, c, 0, 0, 0);
                acc[mt * 4 + nt] = c;
            }
        }
        __syncthreads();
    }
    if (OUT_MODE == 2) {
        const int batch = blockIdx.y >> 1;
#pragma unroll
        for (int nt = 0; nt < 4; nt++) {
            float v = 0.f;
#pragma unroll
            for (int mt = 0; mt < 2; mt++)
#pragma unroll
                for (int r = 0; r < 4; r++)
                    v = fmaxf(v, acc[mt * 4 + nt][r]);
            v = fmaxf(v, __shfl_xor(v, 16));
            v = fmaxf(v, __shfl_xor(v, 32));
            if (lane < 16)
                atomicMax((int*)&outF[(size_t)batch * N + n0 + nt * 16 + lane],
                          __float_as_int(v));
        }
        return;
    }
#pragma unroll
    for (int mt = 0; mt < 2; mt++)
#pragma unroll
        for (int nt = 0; nt < 4; nt++)
#pragma unroll
            for (int r = 0; r < 4; r++) {
                const int m = m0 + mh * 32 + mt * 16 + lq * 4 + r;
                const int n = n0 + nt * 16 + lr;
                float v = fmaxf(acc[mt * 4 + nt][r], 0.f);
                short h, l;
                f2bfpair(v, h, l);
                outH[(size_t)m * N + n] = h;
                outL[(size_t)m * N + n] = l;
            }
}

// ---------------------------------------------------------------------------
// FC layer: grid (O/(4*OPW), B), block 256.
// ---------------------------------------------------------------------------
template<int K, int OPW, int ACT>
__global__ __launch_bounds__(256) void fc_kernel(
    const float* __restrict__ in, const float* __restrict__ w,
    const float* __restrict__ bias, float* __restrict__ out, const int O) {
    const int batch = blockIdx.y;
    const int t = threadIdx.x, lane = t & 63, wv = t >> 6;
    __shared__ float f[K];
    for (int j = t; j < K; j += 256) f[j] = in[batch * K + j];
    __syncthreads();
    const int o0 = blockIdx.x * (4 * OPW) + wv * OPW;
#pragma unroll
    for (int i = 0; i < OPW; i++) {
        const int o = o0 + i;
        const float* wr = w + (size_t)o * K;
        float a = 0.f;
#pragma unroll
        for (int c = lane; c < K; c += 64) a = fmaf(wr[c], f[c], a);
#pragma unroll
        for (int off = 32; off > 0; off >>= 1) a += __shfl_xor(a, off);
        if (lane == 0) {
            float v = a + bias[o];
            out[batch * O + o] = ACT ? fmaxf(v, 0.f) : v;
        }
    }
}

// fc3 (256->40) + softmax fused; one block per batch.
__global__ __launch_bounds__(256) void fc3_softmax_kernel(
    const float* __restrict__ in, const float* __restrict__ w3,
    const float* __restrict__ b3, float* __restrict__ out) {
    const int b = blockIdx.x, t = threadIdx.x, lane = t & 63, wv = t >> 6;
    __shared__ float f[256];
    __shared__ float lg[40];
    f[t] = in[b * 256 + t];
    __syncthreads();
#pragma unroll
    for (int i = 0; i < 10; i++) {
        const int o = wv * 10 + i;
        const float* wr = w3 + (size_t)o * 256;
        float a = 0.f;
#pragma unroll
        for (int c = lane; c < 256; c += 64) a = fmaf(wr[c], f[c], a);
#pragma unroll
        for (int off = 32; off > 0; off >>= 1) a += __shfl_xor(a, off);
        if (lane == 0) lg[o] = a + b3[o];
    }
    __syncthreads();
    if (t < 64) {
        float v = (t < 40) ? lg[t] : -INFINITY;
        float m = v;
#pragma unroll
        for (int off = 32; off > 0; off >>= 1) m = fmaxf(m, __shfl_xor(m, off));
        float e = (t < 40) ? expf(v - m) : 0.f;
        float s = e;
#pragma unroll
        for (int off = 32; off > 0; off >>= 1) s += __shfl_xor(s, off);
        if (t < 40) out[b * 40 + t] = e / s;
    }
}

// ---------------------------------------------------------------------------
extern "C" void kernel_launch(void* const* d_in, const int* in_sizes, int n_in,
                              void* d_out, int out_size, void* d_ws, size_t ws_size,
                              hipStream_t stream) {
    (void)in_sizes; (void)n_in; (void)out_size; (void)ws_size;
    const float* x      = (const float*)d_in[0];
    const float* sa1w0  = (const float*)d_in[1];
    const float* sa1b0  = (const float*)d_in[2];
    const float* sa1w1  = (const float*)d_in[3];
    const float* sa1b1  = (const float*)d_in[4];
    const float* sa1w2  = (const float*)d_in[5];
    const float* sa1b2  = (const float*)d_in[6];
    const float* sa2w0  = (const float*)d_in[7];
    const float* sa2b0  = (const float*)d_in[8];
    const float* sa2w1  = (const float*)d_in[9];
    const float* sa2b1  = (const float*)d_in[10];
    const float* sa2w2  = (const float*)d_in[11];
    const float* sa2b2  = (const float*)d_in[12];
    const float* sa3w0  = (const float*)d_in[13];
    const float* sa3b0  = (const float*)d_in[14];
    const float* sa3w1  = (const float*)d_in[15];
    const float* sa3b1  = (const float*)d_in[16];
    const float* sa3w2  = (const float*)d_in[17];
    const float* sa3b2  = (const float*)d_in[18];
    const float* fc1w   = (const float*)d_in[19];
    const float* fc1b   = (const float*)d_in[20];
    const float* fc2w   = (const float*)d_in[21];
    const float* fc2b   = (const float*)d_in[22];
    const float* fc3w   = (const float*)d_in[23];
    const float* fc3b   = (const float*)d_in[24];
    float* outp = (float*)d_out;

    char* ws = (char*)d_ws;
    size_t off = 0;
    auto alloc = [&](size_t bytes) {
        void* p = ws + off;
        off += (bytes + 255) & ~(size_t)255;
        return p;
    };
    float* nxyz1   = (float*)alloc((size_t)B_ * 512 * 3 * 4);
    int*   idx1    = (int*)  alloc((size_t)B_ * 512 * 32 * 4);
    short* feat1h  = (short*)alloc((size_t)B_ * 512 * 128 * 2);
    short* feat1l  = (short*)alloc((size_t)B_ * 512 * 128 * 2);
    float* nxyz2   = (float*)alloc((size_t)B_ * 128 * 3 * 4);
    int*   idx2    = (int*)  alloc((size_t)B_ * 128 * 64 * 4);
    short* a3h     = (short*)alloc((size_t)4096 * 288 * 2);
    short* a3l     = (short*)alloc((size_t)4096 * 288 * 2);
    short* h3ah    = (short*)alloc((size_t)4096 * 256 * 2);
    short* h3al    = (short*)alloc((size_t)4096 * 256 * 2);
    short* h3bh    = (short*)alloc((size_t)4096 * 512 * 2);
    short* h3bl    = (short*)alloc((size_t)4096 * 512 * 2);
    float* gfeat   = (float*)alloc((size_t)B_ * 1024 * 4);
    float* h1      = (float*)alloc((size_t)B_ * 512 * 4);
    float* h2      = (float*)alloc((size_t)B_ * 256 * 4);
    // split-bf16 weight planes
    short* w1h_s1 = (short*)alloc((size_t)64 * 64 * 2);
    short* w1l_s1 = (short*)alloc((size_t)64 * 64 * 2);
    short* w2h_s1 = (short*)alloc((size_t)128 * 64 * 2);
    short* w2l_s1 = (short*)alloc((size_t)128 * 64 * 2);
    short* w0h_s2 = (short*)alloc((size_t)128 * 160 * 2);
    short* w0l_s2 = (short*)alloc((size_t)128 * 160 * 2);
    short* w1h_s2 = (short*)alloc((size_t)128 * 128 * 2);
    short* w1l_s2 = (short*)alloc((size_t)128 * 128 * 2);
    short* w2h_s2 = (short*)alloc((size_t)256 * 128 * 2);
    short* w2l_s2 = (short*)alloc((size_t)256 * 128 * 2);
    short* w0h_s3 = (short*)alloc((size_t)256 * 288 * 2);
    short* w0l_s3 = (short*)alloc((size_t)256 * 288 * 2);
    short* w1h_s3 = (short*)alloc((size_t)512 * 256 * 2);
    short* w1l_s3 = (short*)alloc((size_t)512 * 256 * 2);
    short* w2h_s3 = (short*)alloc((size_t)1024 * 512 * 2);
    short* w2l_s3 = (short*)alloc((size_t)1024 * 512 * 2);

    // merged {fps stage 1 + weight prep + gfeat zero-init}: fps occupies
    // 32 CUs for its full serial duration; wprep tail blocks fill the rest.
    {
        WDescs W;
        const float* srcs[8] = {sa1w1, sa1w2, sa2w0, sa2w1, sa2w2, sa3w0, sa3w1, sa3w2};
        short* dhs[8] = {w1h_s1, w2h_s1, w0h_s2, w1h_s2, w2h_s2, w0h_s3, w1h_s3, w2h_s3};
        short* dls[8] = {w1l_s1, w2l_s1, w0l_s2, w1l_s2, w2l_s2, w0l_s3, w1l_s3, w2l_s3};
        int Rs[8]  = {64, 128, 128, 128, 256, 256, 512, 1024};
        int Cs[8]  = {64, 64, 131, 128, 128, 259, 256, 512};
        int Cps[8] = {64, 64, 160, 128, 128, 288, 256, 512};
        int blk = 0;
        for (int k = 0; k < 8; k++) {
            W.d[k] = {srcs[k], dhs[k], dls[k], Rs[k], Cs[k], Cps[k], blk,
                      (k == 2) ? 1 : 0};
            blk += (Rs[k] * Cps[k] + 255) / 256;
        }
        W.gfeat = gfeat;
        W.gblk0 = blk;
        W.gtotal = B_ * 1024;
        blk += (B_ * 1024 + 255) / 256;
        fps_wprep_kernel<4096, 512, 256, B_><<<B_ + blk, 256, 0, stream>>>(
            x, nxyz1, W);
    }

    // SA1: {fps2 + ballquery1} merged (fps2 first = overlapped), then
    // {bq2 + sa1} merged (bq2 first = overlapped)
    bq_fps_kernel<B_, 4096, 4096, 32, 512, 512, 128>
        <<<B_ + 4096, 256, 0, stream>>>(
            x, nxyz1, idx1, 0.04f, nxyz1, nxyz2);
    sa1_bq2_kernel<1024><<<1024 + 8192, 256, 0, stream>>>(
        x, nxyz1, idx1, sa1w0, sa1b0,
        w1h_s1, w1l_s1, sa1b1, w2h_s1, w2l_s1, sa1b2, feat1h, feat1l,
        nxyz2, idx2, 0.16f);
    // SA2
    sa2_mfma_kernel<<<B_ * 128, 256, 0, stream>>>(
        nxyz1, feat1h, feat1l, nxyz2, idx2,
        w0h_s2, w0l_s2, sa2b0, w1h_s2, w1l_s2, sa2b1, w2h_s2, w2l_s2, sa2b2,
        a3h, a3l);
    // SA3 (group-all): 3 MFMA GEMMs on planes; gemm3 fuses the maxpool
    mfma_gemm_kernel<1><<<dim3(2, 64), 256, 0, stream>>>(
        a3h, a3l, 288, w0h_s3, w0l_s3, sa3b0, nullptr, h3ah, h3al, 256);
    mfma_gemm_kernel<1><<<dim3(4, 64), 256, 0, stream>>>(
        h3ah, h3al, 256, w1h_s3, w1l_s3, sa3b1, nullptr, h3bh, h3bl, 512);
    mfma_gemm_kernel<2><<<dim3(8, 64), 256, 0, stream>>>(
        h3bh, h3bl, 512, w2h_s3, w2l_s3, sa3b2, gfeat, nullptr, nullptr, 1024);
    // FC head: fc1 (1024->512), fc2 (512->256), fc3+softmax
    fc_kernel<1024, 16, 1><<<dim3(8, B_), 256, 0, stream>>>(
        gfeat, fc1w, fc1b, h1, 512);
    fc_kernel<512, 16, 1><<<dim3(4, B_), 256, 0, stream>>>(
        h1, fc2w, fc2b, h2, 256);
    fc3_softmax_kernel<<<B_, 256, 0, stream>>>(h2, fc3w, fc3b, outp);
}